// Round 2
// baseline (220.243 us; speedup 1.0000x reference)
//
#include <hip/hip_runtime.h>

// Problem constants: B=1, S=4096, D=1024, H=16, W=512, HD=64, C=8 chunks.
typedef __attribute__((ext_vector_type(8))) short short8;
typedef __attribute__((ext_vector_type(4))) float f32x4;

__device__ __forceinline__ unsigned short f2bf(float f) {
  unsigned int u = __float_as_uint(f);
  u += 0x7fffu + ((u >> 16) & 1u);   // round-to-nearest-even
  return (unsigned short)(u >> 16);
}

// ---------------- cast f32 -> bf16 (8 elems/thread) ----------------
__global__ __launch_bounds__(256) void cast_f32_to_bf16(const float* __restrict__ in,
                                                        unsigned short* __restrict__ out,
                                                        int n8) {
  int i = blockIdx.x * 256 + threadIdx.x;
  if (i >= n8) return;
  const f32x4* p = (const f32x4*)in;
  f32x4 a = p[i * 2];
  f32x4 b = p[i * 2 + 1];
  short8 o;
#pragma unroll
  for (int j = 0; j < 4; ++j) o[j] = (short)f2bf(a[j]);
#pragma unroll
  for (int j = 0; j < 4; ++j) o[4 + j] = (short)f2bf(b[j]);
  ((short8*)out)[i] = o;
}

// ---------------- transpose [K][N] f32 -> [N][K] bf16 ----------------
__global__ __launch_bounds__(256) void transpose_cast(const float* __restrict__ w,
                                                      unsigned short* __restrict__ wT,
                                                      int K, int N) {
  __shared__ float tile[32][33];
  int n0 = blockIdx.x * 32, k0 = blockIdx.y * 32;
  int r = threadIdx.x >> 5;   // 0..7
  int c = threadIdx.x & 31;
#pragma unroll
  for (int i = 0; i < 4; ++i)
    tile[r + i * 8][c] = w[(size_t)(k0 + r + i * 8) * N + n0 + c];
  __syncthreads();
#pragma unroll
  for (int i = 0; i < 4; ++i)
    wT[(size_t)(n0 + r + i * 8) * K + k0 + c] = f2bf(tile[c][r + i * 8]);
}

// ---------------- bf16 MFMA GEMM: C[M][N] = A[M][K] * Bt[N][K]^T ----------------
// MODE 0: write f32 to C row-major.
// MODE 1: split cols into q/k/v and write bf16 in [H=16][S=4096][64] head layout.
template <int MODE>
__global__ __launch_bounds__(256) void gemm_bf16(
    const unsigned short* __restrict__ A,
    const unsigned short* __restrict__ Bt,
    float* __restrict__ C,
    unsigned short* __restrict__ q_out,
    unsigned short* __restrict__ k_out,
    unsigned short* __restrict__ v_out,
    int M, int N, int K) {
  __shared__ __align__(16) unsigned short As[128][40];  // +8 pad: stride 80B, conflict-light
  __shared__ __align__(16) unsigned short Bs[128][40];
  const int t = threadIdx.x;
  const int lane = t & 63;
  const int wid = t >> 6;
  const int wm = wid >> 1, wn = wid & 1;  // 2x2 waves, 64x64 each
  const int l15 = lane & 15, lhi = lane >> 4;
  const int m0 = blockIdx.y * 128;
  const int n0 = blockIdx.x * 128;

  f32x4 acc[4][4];
#pragma unroll
  for (int mi = 0; mi < 4; ++mi)
#pragma unroll
    for (int ni = 0; ni < 4; ++ni) acc[mi][ni] = (f32x4){0.f, 0.f, 0.f, 0.f};

  for (int k0 = 0; k0 < K; k0 += 32) {
    short8 av[2], bv[2];
#pragma unroll
    for (int i = 0; i < 2; ++i) {
      int slot = i * 256 + t;
      int row = slot >> 2, g = slot & 3;  // 4 x 16B granules per 32-elem row
      av[i] = *(const short8*)&A[(size_t)(m0 + row) * K + k0 + g * 8];
      bv[i] = *(const short8*)&Bt[(size_t)(n0 + row) * K + k0 + g * 8];
    }
    __syncthreads();  // previous iteration's frag reads complete
#pragma unroll
    for (int i = 0; i < 2; ++i) {
      int slot = i * 256 + t;
      int row = slot >> 2, g = slot & 3;
      *(short8*)&As[row][g * 8] = av[i];
      *(short8*)&Bs[row][g * 8] = bv[i];
    }
    __syncthreads();
    short8 af[4], bf[4];
#pragma unroll
    for (int mi = 0; mi < 4; ++mi)
      af[mi] = *(const short8*)&As[wm * 64 + mi * 16 + l15][lhi * 8];
#pragma unroll
    for (int ni = 0; ni < 4; ++ni)
      bf[ni] = *(const short8*)&Bs[wn * 64 + ni * 16 + l15][lhi * 8];
#pragma unroll
    for (int mi = 0; mi < 4; ++mi)
#pragma unroll
      for (int ni = 0; ni < 4; ++ni)
        acc[mi][ni] = __builtin_amdgcn_mfma_f32_16x16x32_bf16(af[mi], bf[ni], acc[mi][ni], 0, 0, 0);
  }

  // epilogue; C/D layout: col = lane&15, row = (lane>>4)*4 + reg  [HW-verified]
#pragma unroll
  for (int mi = 0; mi < 4; ++mi)
#pragma unroll
    for (int ni = 0; ni < 4; ++ni)
#pragma unroll
      for (int r = 0; r < 4; ++r) {
        int row = m0 + wm * 64 + mi * 16 + lhi * 4 + r;
        int col = n0 + wn * 64 + ni * 16 + l15;
        float val = acc[mi][ni][r];
        if (MODE == 0) {
          C[(size_t)row * N + col] = val;
        } else {
          int which = col >> 10;           // 0:q 1:k 2:v
          int d = col & 1023;
          int hh = d >> 6, hd = d & 63;
          unsigned short* dst = (which == 0) ? q_out : ((which == 1) ? k_out : v_out);
          dst[((size_t)hh * 4096 + row) * 64 + hd] = f2bf(val);
        }
      }
}

// ---------------- sliding-window flash attention ----------------
// Grid: (qt=4, c=8, h=16). Block: 256 thr = 4 waves, each wave owns 32 queries.
// Per (h,c): Q[512][64] attends to context keys j in [0,1024) = [prev chunk | cur chunk].
// Mask: q_in_chunk + 512 >= j ; chunk 0 has no prev (we simply skip kt < 8).
__global__ __launch_bounds__(256) void attn_kernel(
    const unsigned short* __restrict__ qh,   // [16][4096][64] bf16
    const unsigned short* __restrict__ kh,
    const unsigned short* __restrict__ vh,
    unsigned short* __restrict__ out) {      // [4096][1024] bf16
  __shared__ __align__(16) unsigned short Qs[128][72];
  __shared__ __align__(16) unsigned short Ks[64][72];
  __shared__ __align__(16) unsigned short Vt[64][72];     // [hd][key]
  __shared__ __align__(16) unsigned short Pl[4][32][72];  // per-wave P tile

  const int t = threadIdx.x;
  const int lane = t & 63;
  const int w = t >> 6;
  const int l15 = lane & 15;
  const int lhi = lane >> 4;
  const int qt = blockIdx.x;
  const int c = blockIdx.y;
  const int h = blockIdx.z;

  const long head_base = (long)h * 4096 * 64;
  const int q0 = qt * 128;  // query offset within chunk
  const long q_gbase = head_base + (long)(c * 512 + q0) * 64;

  // stage Q tile [128][64]
#pragma unroll
  for (int i = 0; i < 4; ++i) {
    int slot = i * 256 + t;
    int r = slot >> 3, g = slot & 7;
    *(short8*)&Qs[r][g * 8] = *(const short8*)&qh[q_gbase + (long)r * 64 + g * 8];
  }

  float m_run[8], l_run[8];  // indexed mi*4+r ; row = q0 + w*32 + mi*16 + lhi*4 + r
  f32x4 acc_o[2][4];
#pragma unroll
  for (int i = 0; i < 8; ++i) { m_run[i] = -1e30f; l_run[i] = 0.f; }
#pragma unroll
  for (int mi = 0; mi < 2; ++mi)
#pragma unroll
    for (int ni = 0; ni < 4; ++ni) acc_o[mi][ni] = (f32x4){0.f, 0.f, 0.f, 0.f};

  const int kt_start = (c == 0) ? 8 : 0;     // chunk 0: no prev chunk
  const int kt_end = 2 * qt + 9;             // causal trim: j_max = qt*128+639
  const long kv_base = head_base + ((long)c - 1) * 512 * 64;  // j=0 -> key (c-1)*512

  for (int kt = kt_start; kt <= kt_end; ++kt) {
    const int j0 = kt * 64;
    __syncthreads();  // prior tile's LDS reads done
    // stage K[64][64] and V^T[64][64]
#pragma unroll
    for (int i = 0; i < 2; ++i) {
      int slot = i * 256 + t;
      int r = slot >> 3, g = slot & 7;
      *(short8*)&Ks[r][g * 8] = *(const short8*)&kh[kv_base + (long)(j0 + r) * 64 + g * 8];
      short8 vv = *(const short8*)&vh[kv_base + (long)(j0 + r) * 64 + g * 8];
#pragma unroll
      for (int j = 0; j < 8; ++j) Vt[g * 8 + j][r] = (unsigned short)vv[j];
    }
    __syncthreads();

    // QK^T: 32 queries x 64 keys per wave
    f32x4 sa[2][4];
#pragma unroll
    for (int mi = 0; mi < 2; ++mi)
#pragma unroll
      for (int ni = 0; ni < 4; ++ni) sa[mi][ni] = (f32x4){0.f, 0.f, 0.f, 0.f};
#pragma unroll
    for (int kc = 0; kc < 2; ++kc) {
      short8 qf[2], kf[4];
#pragma unroll
      for (int mi = 0; mi < 2; ++mi)
        qf[mi] = *(const short8*)&Qs[w * 32 + mi * 16 + l15][kc * 32 + lhi * 8];
#pragma unroll
      for (int ni = 0; ni < 4; ++ni)
        kf[ni] = *(const short8*)&Ks[ni * 16 + l15][kc * 32 + lhi * 8];
#pragma unroll
      for (int mi = 0; mi < 2; ++mi)
#pragma unroll
        for (int ni = 0; ni < 4; ++ni)
          sa[mi][ni] = __builtin_amdgcn_mfma_f32_16x16x32_bf16(qf[mi], kf[ni], sa[mi][ni], 0, 0, 0);
    }

    // scale + causal mask + online softmax
    const int qrow0 = q0 + w * 32 + lhi * 4;
    float tmax[8];
#pragma unroll
    for (int i = 0; i < 8; ++i) tmax[i] = -1e30f;
#pragma unroll
    for (int mi = 0; mi < 2; ++mi)
#pragma unroll
      for (int ni = 0; ni < 4; ++ni) {
        int jj = j0 + ni * 16 + l15;
#pragma unroll
        for (int r = 0; r < 4; ++r) {
          float sv = sa[mi][ni][r] * 0.125f;
          int qq = qrow0 + mi * 16 + r;
          sv = (qq + 512 >= jj) ? sv : -1e30f;
          sa[mi][ni][r] = sv;
          tmax[mi * 4 + r] = fmaxf(tmax[mi * 4 + r], sv);
        }
      }
#pragma unroll
    for (int i = 0; i < 8; ++i)
#pragma unroll
      for (int d = 1; d < 16; d <<= 1)
        tmax[i] = fmaxf(tmax[i], __shfl_xor(tmax[i], d, 64));

    float corr[8], rsum[8];
#pragma unroll
    for (int i = 0; i < 8; ++i) {
      float mn = fmaxf(m_run[i], tmax[i]);
      corr[i] = __expf(m_run[i] - mn);
      m_run[i] = mn;
      rsum[i] = 0.f;
    }
#pragma unroll
    for (int mi = 0; mi < 2; ++mi)
#pragma unroll
      for (int ni = 0; ni < 4; ++ni)
#pragma unroll
        for (int r = 0; r < 4; ++r) {
          float p = __expf(sa[mi][ni][r] - m_run[mi * 4 + r]);
          rsum[mi * 4 + r] += p;
          Pl[w][mi * 16 + lhi * 4 + r][ni * 16 + l15] = f2bf(p);
        }
#pragma unroll
    for (int i = 0; i < 8; ++i) {
#pragma unroll
      for (int d = 1; d < 16; d <<= 1) rsum[i] += __shfl_xor(rsum[i], d, 64);
      l_run[i] = l_run[i] * corr[i] + rsum[i];
    }
#pragma unroll
    for (int mi = 0; mi < 2; ++mi)
#pragma unroll
      for (int ni = 0; ni < 4; ++ni)
#pragma unroll
        for (int r = 0; r < 4; ++r) acc_o[mi][ni][r] *= corr[mi * 4 + r];

    // PV: O[32][64] += P[32][64] * V[64][64]
#pragma unroll
    for (int k2 = 0; k2 < 2; ++k2) {
      short8 pf[2];
#pragma unroll
      for (int mi = 0; mi < 2; ++mi)
        pf[mi] = *(const short8*)&Pl[w][mi * 16 + l15][k2 * 32 + lhi * 8];
#pragma unroll
      for (int ni = 0; ni < 4; ++ni) {
        short8 vf = *(const short8*)&Vt[ni * 16 + l15][k2 * 32 + lhi * 8];
#pragma unroll
        for (int mi = 0; mi < 2; ++mi)
          acc_o[mi][ni] = __builtin_amdgcn_mfma_f32_16x16x32_bf16(pf[mi], vf, acc_o[mi][ni], 0, 0, 0);
      }
    }
  }

  // normalize + write [S][D] bf16 (head-interleaved cols)
#pragma unroll
  for (int mi = 0; mi < 2; ++mi)
#pragma unroll
    for (int ni = 0; ni < 4; ++ni)
#pragma unroll
      for (int r = 0; r < 4; ++r) {
        int qq = q0 + w * 32 + mi * 16 + lhi * 4 + r;
        long s = (long)c * 512 + qq;
        int col = h * 64 + ni * 16 + l15;
        float o = acc_o[mi][ni][r] / l_run[mi * 4 + r];
        out[s * 1024 + col] = f2bf(o);
      }
}

extern "C" void kernel_launch(void* const* d_in, const int* in_sizes, int n_in,
                              void* d_out, int out_size, void* d_ws, size_t ws_size,
                              hipStream_t stream) {
  const float* x = (const float*)d_in[0];      // [4096][1024]
  const float* w_qkv = (const float*)d_in[1];  // [1024][3072]
  const float* w_out = (const float*)d_in[2];  // [1024][1024]
  float* out = (float*)d_out;                  // [4096][1024]

  unsigned short* xb = (unsigned short*)d_ws;        // 4096*1024
  unsigned short* wqkvT = xb + 4096 * 1024;          // [3072][1024]
  unsigned short* woutT = wqkvT + 3072 * 1024;       // [1024][1024]
  unsigned short* qh = woutT + 1024 * 1024;          // [16][4096][64]
  unsigned short* kh = qh + 16 * 4096 * 64;
  unsigned short* vh = kh + 16 * 4096 * 64;
  unsigned short* attn = xb;  // alias: x_bf16 dead after GEMM1  (total ws = 40 MB)

  cast_f32_to_bf16<<<2048, 256, 0, stream>>>(x, xb, 4096 * 1024 / 8);
  transpose_cast<<<dim3(96, 32), 256, 0, stream>>>(w_qkv, wqkvT, 1024, 3072);
  transpose_cast<<<dim3(32, 32), 256, 0, stream>>>(w_out, woutT, 1024, 1024);

  gemm_bf16<1><<<dim3(24, 32), 256, 0, stream>>>(xb, wqkvT, nullptr, qh, kh, vh,
                                                 4096, 3072, 1024);
  attn_kernel<<<dim3(4, 8, 16), 256, 0, stream>>>(qh, kh, vh, attn);
  gemm_bf16<0><<<dim3(8, 32), 256, 0, stream>>>(attn, woutT, out, nullptr, nullptr, nullptr,
                                                4096, 1024, 1024);
}